// Round 1
// baseline (432.735 us; speedup 1.0000x reference)
//
#include <hip/hip_runtime.h>
#include <hip/hip_bf16.h>
#include <stdint.h>

// Problem constants (fixed by the reference)
static constexpr int BB = 16, CC_ = 128, HH = 128, WW = 128;

typedef float  f32x4 __attribute__((ext_vector_type(4)));
typedef short  s16x8 __attribute__((ext_vector_type(8)));
typedef uint32_t u32x4 __attribute__((ext_vector_type(4)));

// round-to-nearest-even float -> bf16 bits (data has no NaN/Inf)
__device__ __forceinline__ uint16_t f2bf(float f) {
    union { float f; uint32_t u; } a; a.f = f;
    uint32_t r = a.u + 0x7FFFu + ((a.u >> 16) & 1u);
    return (uint16_t)(r >> 16);
}

__device__ __forceinline__ float lrelu(float v) { return fmaxf(v, 0.1f * v); }

// ---------------------------------------------------------------------------
// Prep kernel: blocks 0..15 -> per-sample depthwise kernels + CA attention.
// Block 16 -> pack conv_w (128x128) into MFMA A-fragment order as bf16:
//   Wp[((mt*4+kk)*64 + lane)*8 + j] = conv_w[o=mt*16+(lane&15)][c=kk*32+(lane>>4)*8+j]
// ---------------------------------------------------------------------------
__global__ __launch_bounds__(128) void prep_kernel(
    const float* __restrict__ deg, const float* __restrict__ w1,
    const float* __restrict__ w2, const float* __restrict__ conv_w,
    const float* __restrict__ ca_w1, const float* __restrict__ ca_w2,
    float* __restrict__ kern_ws, float* __restrict__ att_ws,
    uint16_t* __restrict__ Wp)
{
    const int t = threadIdx.x;
    if (blockIdx.x < 16) {
        const int b = blockIdx.x;
        __shared__ float sdeg[128];
        __shared__ float shid[128];
        __shared__ float sh2[16];
        sdeg[t] = deg[b * 128 + t];
        __syncthreads();
        // hidden = lrelu(deg @ w1^T);  w1 is (out=128, in=128)
        {
            float acc = 0.f;
            const float* w1r = w1 + t * 128;
            for (int c = 0; c < 128; ++c) acc += sdeg[c] * w1r[c];
            shid[t] = lrelu(acc);
        }
        if (t < 16) {
            float a2 = 0.f;
            const float* cw = ca_w1 + t * 128;
            for (int c = 0; c < 128; ++c) a2 += sdeg[c] * cw[c];
            sh2[t] = lrelu(a2);
        }
        __syncthreads();
        // CA attention: sigmoid(hidden2 @ ca_w2^T)  (ca_w2 is (128,16))
        {
            float aa = 0.f;
            const float* c2 = ca_w2 + t * 16;
            #pragma unroll
            for (int r = 0; r < 16; ++r) aa += sh2[r] * c2[r];
            att_ws[b * 128 + t] = 1.f / (1.f + expf(-aa));
        }
        // kern taps: (hidden @ w2^T)[c*9 + tap]; store padded [c][12] for float4 loads
        for (int j = 0; j < 9; ++j) {
            float kv = 0.f;
            const float* w2r = w2 + (t * 9 + j) * 128;
            for (int r = 0; r < 128; ++r) kv += shid[r] * w2r[r];
            kern_ws[(b * 128 + t) * 12 + j] = kv;
        }
        // zero the pad so stray loads are benign
        kern_ws[(b * 128 + t) * 12 + 9]  = 0.f;
        kern_ws[(b * 128 + t) * 12 + 10] = 0.f;
        kern_ws[(b * 128 + t) * 12 + 11] = 0.f;
    } else {
        for (int idx = t; idx < 16384; idx += 128) {
            int j    = idx & 7;
            int lane = (idx >> 3) & 63;
            int kk   = (idx >> 9) & 3;
            int mt   = idx >> 11;
            int o = mt * 16 + (lane & 15);
            int c = kk * 32 + ((lane >> 4) & 3) * 8 + j;
            Wp[idx] = f2bf(conv_w[o * 128 + c]);
        }
    }
}

// ---------------------------------------------------------------------------
// Main fused kernel: one block per (b, h) row. 256 threads = 4 waves.
// Phase 1: depthwise 3x3 + lrelu -> bf16 y tile in LDS, layout (w, c) with
//          XOR swizzle  byte ^= ((w&7)^((w>>3)&7))<<4  (bank-uniform for both
//          the b128 writes and the b128 B-fragment reads).
// Phase 2: 1x1 conv as MFMA GEMM out[o][w] = sum_c W[o][c] * y[c][w],
//          bias folded into acc init; epilogue adds x0 * att (residual).
// ---------------------------------------------------------------------------
__global__ __launch_bounds__(256, 2) void main_kernel(
    const float* __restrict__ x0, const float* __restrict__ kern_ws,
    const float* __restrict__ att_ws, const uint16_t* __restrict__ Wp,
    const float* __restrict__ conv_b, float* __restrict__ out)
{
    __shared__ uint16_t y_s[128 * 128]; // 32 KiB, accessed by swizzled byte offset

    // XCD-aware swizzle: consecutive logical (b,h) rows land on the same XCD
    // (2048 % 8 == 0 -> bijective). Adjacent rows share 2 of 3 halo rows -> L2 hits.
    const int bid = blockIdx.x;
    const int lg  = (bid & 7) * 256 + (bid >> 3);
    const int b = lg >> 7;
    const int h = lg & 127;

    const int t    = threadIdx.x;
    const int lane = t & 63;
    const int q    = t >> 6;          // wave id 0..3
    const int c0   = (t >> 4) * 8;    // this thread's channel octet
    const int w0   = (t & 15) * 8;    // this thread's w range

    // ---- load kern taps for my 8 channels (global, L1/L2-hot: 4.6KB per b) ----
    float kf[8][9];
    #pragma unroll
    for (int cc = 0; cc < 8; ++cc) {
        const float* kp = kern_ws + (b * 128 + c0 + cc) * 12;
        f32x4 ka = *(const f32x4*)kp;
        f32x4 kb = *(const f32x4*)(kp + 4);
        float k8 = kp[8];
        kf[cc][0] = ka.x; kf[cc][1] = ka.y; kf[cc][2] = ka.z; kf[cc][3] = ka.w;
        kf[cc][4] = kb.x; kf[cc][5] = kb.y; kf[cc][6] = kb.z; kf[cc][7] = kb.w;
        kf[cc][8] = k8;
    }

    // ---- depthwise 3x3 + lrelu -> packed bf16 ----
    uint32_t ypk[8][4];
    #pragma unroll
    for (int cc = 0; cc < 8; ++cc) {
        const int c = c0 + cc;
        const float* xpl = x0 + (b * 128 + c) * (128 * 128); // channel plane
        float a8[8];
        #pragma unroll
        for (int i = 0; i < 8; ++i) a8[i] = 0.f;
        #pragma unroll
        for (int dr = 0; dr < 3; ++dr) {
            const int r = h - 1 + dr;
            f32x4 f0, f1;
            if ((unsigned)r < 128u) {
                const float* rp = xpl + r * 128 + w0;
                f0 = *(const f32x4*)rp;
                f1 = *(const f32x4*)(rp + 4);
            } else {
                f0.x = f0.y = f0.z = f0.w = 0.f;
                f1.x = f1.y = f1.z = f1.w = 0.f;
            }
            // halo columns from neighbor lanes (same c within a 16-lane w-group)
            float lft = __shfl(f1.w, (lane - 1) & 63);
            float rgt = __shfl(f0.x, (lane + 1) & 63);
            if ((t & 15) == 0)  lft = 0.f;   // w == 0 boundary
            if ((t & 15) == 15) rgt = 0.f;   // w == 127 boundary
            const float k0 = kf[cc][dr * 3 + 0];
            const float k1 = kf[cc][dr * 3 + 1];
            const float k2 = kf[cc][dr * 3 + 2];
            a8[0] += k0 * lft  + k1 * f0.x + k2 * f0.y;
            a8[1] += k0 * f0.x + k1 * f0.y + k2 * f0.z;
            a8[2] += k0 * f0.y + k1 * f0.z + k2 * f0.w;
            a8[3] += k0 * f0.z + k1 * f0.w + k2 * f1.x;
            a8[4] += k0 * f0.w + k1 * f1.x + k2 * f1.y;
            a8[5] += k0 * f1.x + k1 * f1.y + k2 * f1.z;
            a8[6] += k0 * f1.y + k1 * f1.z + k2 * f1.w;
            a8[7] += k0 * f1.z + k1 * f1.w + k2 * rgt;
        }
        #pragma unroll
        for (int wi = 0; wi < 8; ++wi) {
            uint32_t u = f2bf(lrelu(a8[wi]));
            if ((cc & 1) == 0) ypk[wi][cc >> 1] = u;
            else               ypk[wi][cc >> 1] |= (u << 16);
        }
    }
    // write y tile: 8 consecutive c (bf16) per b128 write, one per w
    #pragma unroll
    for (int wi = 0; wi < 8; ++wi) {
        const int w = w0 + wi;
        int off = w * 256 + c0 * 2;
        off ^= (((w & 7) ^ ((w >> 3) & 7)) << 4);
        u32x4 v; v.x = ypk[wi][0]; v.y = ypk[wi][1]; v.z = ypk[wi][2]; v.w = ypk[wi][3];
        *(u32x4*)((char*)y_s + off) = v;
    }

    // ---- GEMM setup: wave q owns m-half (q>>1) x n-half (q&1): 4x4 16x16 tiles ----
    const int ah = q >> 1;   // o-half
    const int nh = q & 1;    // w-half
    s16x8 Af[4][4];
    #pragma unroll
    for (int mt = 0; mt < 4; ++mt)
        #pragma unroll
        for (int kk = 0; kk < 4; ++kk)
            Af[mt][kk] = *(const s16x8*)(Wp + (((ah * 4 + mt) * 4 + kk) * 64 + lane) * 8);

    float cbv[4][4], atv[4][4];
    #pragma unroll
    for (int mt = 0; mt < 4; ++mt)
        #pragma unroll
        for (int r = 0; r < 4; ++r) {
            const int o = (ah * 4 + mt) * 16 + (lane >> 4) * 4 + r;
            cbv[mt][r] = conv_b[o];
            atv[mt][r] = att_ws[b * 128 + o];
        }

    __syncthreads();

    f32x4 acc[4][4];
    #pragma unroll
    for (int mt = 0; mt < 4; ++mt)
        #pragma unroll
        for (int nt = 0; nt < 4; ++nt) {
            acc[mt][nt].x = cbv[mt][0];
            acc[mt][nt].y = cbv[mt][1];
            acc[mt][nt].z = cbv[mt][2];
            acc[mt][nt].w = cbv[mt][3];
        }

    #pragma unroll
    for (int nt = 0; nt < 4; ++nt) {
        const int w = (nh * 4 + nt) * 16 + (lane & 15);
        const int swz = (((w & 7) ^ ((w >> 3) & 7)) << 4);
        #pragma unroll
        for (int kk = 0; kk < 4; ++kk) {
            const int off = (w * 256 + kk * 64 + (lane >> 4) * 16) ^ swz;
            s16x8 Bf = *(const s16x8*)((const char*)y_s + off);
            #pragma unroll
            for (int mt = 0; mt < 4; ++mt)
                acc[mt][nt] = __builtin_amdgcn_mfma_f32_16x16x32_bf16(
                    Af[mt][kk], Bf, acc[mt][nt], 0, 0, 0);
        }
    }

    // ---- epilogue: + x0 * att (bias already in acc), store f32 ----
    #pragma unroll
    for (int mt = 0; mt < 4; ++mt)
        #pragma unroll
        for (int nt = 0; nt < 4; ++nt) {
            const int w = (nh * 4 + nt) * 16 + (lane & 15);
            #pragma unroll
            for (int r = 0; r < 4; ++r) {
                const int o = (ah * 4 + mt) * 16 + (lane >> 4) * 4 + r;
                const int idx = ((b * 128 + o) * 128 + h) * 128 + w;
                out[idx] = acc[mt][nt][r] + x0[idx] * atv[mt][r];
            }
        }
}

// ---------------------------------------------------------------------------
extern "C" void kernel_launch(void* const* d_in, const int* in_sizes, int n_in,
                              void* d_out, int out_size, void* d_ws, size_t ws_size,
                              hipStream_t stream) {
    const float* x0     = (const float*)d_in[0];
    const float* deg    = (const float*)d_in[1];
    const float* w1     = (const float*)d_in[2];
    const float* w2     = (const float*)d_in[3];
    const float* conv_w = (const float*)d_in[4];
    const float* conv_b = (const float*)d_in[5];
    const float* ca_w1  = (const float*)d_in[6];
    const float* ca_w2  = (const float*)d_in[7];
    float* out = (float*)d_out;

    // workspace layout (all 16B aligned): kern 96KB | att 8KB | Wp 32KB
    float* kern_ws = (float*)d_ws;
    float* att_ws  = kern_ws + 16 * 128 * 12;
    uint16_t* Wp   = (uint16_t*)(att_ws + 16 * 128);

    prep_kernel<<<17, 128, 0, stream>>>(deg, w1, w2, conv_w, ca_w1, ca_w2,
                                        kern_ws, att_ws, Wp);
    main_kernel<<<2048, 256, 0, stream>>>(x0, kern_ws, att_ws, Wp, conv_b, out);
}